// Round 9
// baseline (313.041 us; speedup 1.0000x reference)
//
#include <hip/hip_runtime.h>

// WordSAGE on MI355X — fp32 in/out. Round-19 = round-18 resubmitted (r8 was
// an infra failure: "MI355X container failed twice", no kernel signal).
//   k_prep : edge phase BUCKETS by dst>>5 (625 buckets = one per k_mega
//            block): atomicAdd on 625 counters + dense 4B append of
//            (dst&31)<<16|src. Kills the per-dst CSR random 2B scatter that
//            wrote back ~31MB for 1.25MB of payload (r7: WRITE 34.5MB,
//            VALUBusy 0.5% -> pure store/atomic latency).
//   k_mega : stages its own bucket (coalesced ~4KB), counting-sorts into a
//            per-row LDS CSR via 32 LDS-atomic bumps, then the r7 pipelined
//            gather||MFMA runs unchanged (indices now from LDS). Per-row
//            counts come from the sort -> global cnt buffer + 80KB memset
//            gone (memset now 2.5KB). Cap-96/true-count policy unchanged.
// Precision: weights/agg/h split hi+lo bf16; train & gene hi-only (RNE).

#define NG 2500
#define NT 20000
#define NE 640000
#define NCLS 16
#define CAP 96
#define BCAP 1536   // bucket capacity (mean 1024, ~16 sigma headroom)

typedef unsigned short u16;
typedef unsigned int u32;

typedef float f32x4 __attribute__((ext_vector_type(4)));
typedef __bf16 bf16x8 __attribute__((ext_vector_type(8)));

__device__ __forceinline__ float b2f(u16 u) { return __uint_as_float(((u32)u) << 16); }
__device__ __forceinline__ float blo(u32 p) { return __uint_as_float(p << 16); }
__device__ __forceinline__ float bhi(u32 p) { return __uint_as_float(p & 0xffff0000u); }
__device__ __forceinline__ u16 f2b(float f) {  // RNE fp32->bf16
    u32 u = __float_as_uint(f);
    return (u16)((u + 0x7fffu + ((u >> 16) & 1u)) >> 16);
}

// ---- sizes ---------------------------------------------------------------
#define B1N 81920   // K=640: train k 0..499, zero 500..511, agg 512..639; N=128
#define B2N 32768   // K=256: h1 (W2s) 0..127, agg (W2n) 128..255; N=128
#define B3N 16384   // K=128 Wc1, N=128
#define B4N 2048    // K=128 Wc2, N=16
#define NEB 625     // edge blocks (4 edges/thread via int4)
#define GNB 625     // gene-convert blocks
#define PKB 520     // pack blocks

// ---- fused prep -----------------------------------------------------------
__global__ __launch_bounds__(256) void k_prep(
    const int* __restrict__ esrc, const int* __restrict__ edst,
    int* __restrict__ bcnt, u32* __restrict__ bkt,
    const float* __restrict__ gene, u32* __restrict__ GH32,
    const float* __restrict__ W1n, const float* __restrict__ W1s,
    const float* __restrict__ W2n, const float* __restrict__ W2s,
    const float* __restrict__ Wc1, const float* __restrict__ Wc2,
    u16* __restrict__ B1h, u16* __restrict__ B1l,
    u16* __restrict__ B2h, u16* __restrict__ B2l,
    u16* __restrict__ B3h, u16* __restrict__ B3l,
    u16* __restrict__ B4h, u16* __restrict__ B4l) {
    int blk = blockIdx.x, t = threadIdx.x;
    if (blk < NEB) {
        int e0 = (blk * 256 + t) * 4;
        const int4 s4 = *(const int4*)(esrc + e0);
        const int4 d4 = *(const int4*)(edst + e0);
        int ss[4] = {s4.x, s4.y, s4.z, s4.w};
        int dd[4] = {d4.x, d4.y, d4.z, d4.w};
#pragma unroll
        for (int i = 0; i < 4; ++i) {   // 4 independent atomic chains
            unsigned d = (unsigned)dd[i];
            if (d < NT) {
                int b = (int)(d >> 5);
                int pos = atomicAdd(&bcnt[b], 1);
                if (pos < BCAP)
                    bkt[(size_t)b * BCAP + pos] = ((d & 31u) << 16) | (u32)ss[i];
            }
        }
        return;
    }
    if (blk < NEB + GNB) {
        int idx = (blk - NEB) * 256 + t;  // < 160000
        float2 v = ((const float2*)gene)[idx];
        GH32[idx] = (u32)f2b(v.x) | ((u32)f2b(v.y) << 16);
        return;
    }
    // ---- weight pack (split hi/lo, B-fragment order) ----
    int idx = (blk - NEB - GNB) * 256 + t;
    float v = 0.f;
    u16 *ph = 0, *pl = 0;
    int off = 0;
    if (idx < B1N) {
        int j = idx & 7, l = (idx >> 3) & 63, rest = idx >> 9;
        int g = rest & 7, kk = rest >> 3;
        int k = kk * 32 + ((l >> 4) << 3) + j, n = (g << 4) + (l & 15);
        if (k < 500) v = W1s[k * 128 + n];
        else if (k >= 512) v = W1n[(k - 512) * 128 + n];
        ph = B1h; pl = B1l; off = idx;
    } else if (idx < B1N + B2N) {
        int e = idx - B1N;
        int j = e & 7, l = (e >> 3) & 63, rest = e >> 9;
        int g = rest & 7, kk = rest >> 3;
        int k = kk * 32 + ((l >> 4) << 3) + j, n = (g << 4) + (l & 15);
        v = (k < 128) ? W2s[k * 128 + n] : W2n[(k - 128) * 128 + n];
        ph = B2h; pl = B2l; off = e;
    } else if (idx < B1N + B2N + B3N) {
        int e = idx - (B1N + B2N);
        int j = e & 7, l = (e >> 3) & 63, rest = e >> 9;
        int g = rest & 7, kk = rest >> 3;
        int k = kk * 32 + ((l >> 4) << 3) + j, n = (g << 4) + (l & 15);
        v = Wc1[k * 128 + n];
        ph = B3h; pl = B3l; off = e;
    } else if (idx < B1N + B2N + B3N + B4N) {
        int e = idx - (B1N + B2N + B3N);
        int j = e & 7, l = (e >> 3) & 63, kk = e >> 9;
        int k = kk * 32 + ((l >> 4) << 3) + j, n = l & 15;
        v = Wc2[k * 16 + n];
        ph = B4h; pl = B4l; off = e;
    }
    if (ph) {
        u16 hi = f2b(v);
        u16 lo = f2b(v - b2f(hi));
        ph[off] = hi;
        pl[off] = lo;
    }
}

// ---- fused sort + gather + stage + 4-layer MFMA ----------------------------
// Block: 512 thr (8 waves), 32 rows (2 tiles). wave = col-group g (0..7);
// each wave handles BOTH row-tiles (acc0/acc1) -> B bytes read once/block.
// Shared pool (u16 units):
//   SAGh @0      [32*136]    SAGl @4352  [32*136]
//   S1h  @8704   [32*136]    S1l  @13056 [32*136]
//   S2h  @17408  [32*136]    S2l  @21760 [32*136]
//   TS   @8704   [32*520]  (train tile bf16, overlays S1h..S2l; all TS reads
//                           complete before the post-gather barrier)
// Plus separate: SRT [32*96] per-row LDS CSR, POS[32] bump counters.
__global__ __launch_bounds__(512, 3) void k_mega(
    const int* __restrict__ bcnt, const u32* __restrict__ bkt,
    const u16* __restrict__ GH, const float* __restrict__ train,
    const u16* __restrict__ B1h, const u16* __restrict__ B1l,
    const u16* __restrict__ B2h, const u16* __restrict__ B2l,
    const u16* __restrict__ B3h, const u16* __restrict__ B3l,
    const u16* __restrict__ B4h, const u16* __restrict__ B4l,
    const float* __restrict__ b1, const float* __restrict__ b2,
    const float* __restrict__ bc1, const float* __restrict__ bc2,
    float* __restrict__ out) {
    __shared__ __align__(16) u16 SMEM[26112];   // 52224 B
    __shared__ __align__(16) u16 SRT[32 * CAP]; // 6144 B per-row lists
    __shared__ int POS[32];
    u16* SAGh = SMEM;
    u16* SAGl = SMEM + 4352;
    u16* S1h = SMEM + 8704;
    u16* S1l = SMEM + 13056;
    u16* S2h = SMEM + 17408;
    u16* S2l = SMEM + 21760;
    u16* TS = SMEM + 8704;                      // overlays S1h..S2l

    int t = threadIdx.x;
    int row0 = blockIdx.x * 32;

    // ---- phase 0a: issue train-tile loads (latency hides under sort) ----
    float4 st[8];
    {
        const float4* tb = (const float4*)(train + (size_t)row0 * 500);
#pragma unroll
        for (int i = 0; i < 7; ++i) st[i] = tb[t + i * 512];
        if (t < 416) st[7] = tb[t + 3584];      // 4000 float4 = 32 rows x 125
    }

    if (t < 32) POS[t] = 0;
    int bc = bcnt[blockIdx.x];
    if (bc > BCAP) bc = BCAP;
    __syncthreads();

    // ---- phase 0b: counting-scatter bucket -> per-row LDS CSR ----
    for (int i = t; i < bc; i += 512) {
        u32 e = bkt[(size_t)blockIdx.x * BCAP + i];  // coalesced
        int r = (int)(e >> 16);
        int p = atomicAdd(&POS[r], 1);
        if (p < CAP) SRT[r * CAP + p] = (u16)(e & 0xffffu);
    }

    // ---- phase 0c: convert staged tile -> TS (row-major [32][520] bf16) ----
    {
        u32* T32 = (u32*)TS;
#pragma unroll
        for (int i = 0; i < 8; ++i) {
            int idx = t + i * 512;
            if (i == 7 && t >= 416) break;
            int r = idx / 125, c4 = idx - r * 125;
            int base = r * 260 + c4 * 2;       // u32 units; row stride 520 u16
            T32[base] = (u32)f2b(st[i].x) | ((u32)f2b(st[i].y) << 16);
            T32[base + 1] = (u32)f2b(st[i].z) | ((u32)f2b(st[i].w) << 16);
        }
        if (t < 192) {                          // zero cols 500..511
            int r = t / 6, c4 = t - r * 6;
            T32[r * 260 + 250 + c4] = 0;
        }
    }
    __syncthreads();   // SRT + POS + TS ready

    int lane = t & 63, g = t >> 6;  // wave index = col-group 0..7
    int m = lane & 15, q = lane >> 4, n16 = lane & 15;
    int gr = t >> 4, cg = t & 15;   // gather row 0..31, col-group 0..15

    int ctrue = POS[gr];
    int c = ctrue > CAP ? CAP : ctrue;
    const u16* crow = SRT + gr * CAP;
    int nfull = c >> 3;
    uint4 i40 = *(const uint4*)(crow);          // LDS, 16-lane broadcast
    uint4 i41 = *(const uint4*)(crow + 8);
    uint4 i42 = *(const uint4*)(crow + 16);
    uint4 i43 = *(const uint4*)(crow + 24);
    float a[8];
#pragma unroll
    for (int p = 0; p < 8; ++p) a[p] = 0.f;

    int hr0 = m * 136 + q * 8;
    int hr1 = (16 + m) * 136 + q * 8;
    int cr0 = q * 4, cr1 = 16 + q * 4;
    const f32x4 z4 = {0.f, 0.f, 0.f, 0.f};
    f32x4 acc0 = z4, acc1 = z4;
    const u16* tA0 = TS + m * 520 + q * 8;
    const u16* tA1 = TS + (16 + m) * 520 + q * 8;

#define ACC(p)                                      \
    do {                                            \
        a[0] += blo((p).x); a[1] += bhi((p).x);     \
        a[2] += blo((p).y); a[3] += bhi((p).y);     \
        a[4] += blo((p).z); a[5] += bhi((p).z);     \
        a[6] += blo((p).w); a[7] += bhi((p).w);     \
    } while (0)

    auto GHLoad = [&](int s) -> uint4 {
        return *(const uint4*)(GH + (size_t)s * 128 + cg * 8);
    };
    uint4 P0, P1, P2, P3, P4, P5, P6, P7;
    auto issue8 = [&](uint4 iq) {
        P0 = GHLoad((int)(iq.x & 0xffffu)); P1 = GHLoad((int)(iq.x >> 16));
        P2 = GHLoad((int)(iq.y & 0xffffu)); P3 = GHLoad((int)(iq.y >> 16));
        P4 = GHLoad((int)(iq.z & 0xffffu)); P5 = GHLoad((int)(iq.z >> 16));
        P6 = GHLoad((int)(iq.w & 0xffffu)); P7 = GHLoad((int)(iq.w >> 16));
    };
    auto acc8 = [&]() {
        ACC(P0); ACC(P1); ACC(P2); ACC(P3);
        ACC(P4); ACC(P5); ACC(P6); ACC(P7);
    };
    auto kk4 = [&](int base) {
#pragma unroll
        for (int kk = base; kk < base + 4; ++kk) {
            bf16x8 a0 = *(const bf16x8*)(tA0 + kk * 32);
            bf16x8 a1 = *(const bf16x8*)(tA1 + kk * 32);
            size_t bo = ((size_t)(kk * 8 + g) * 64 + lane) * 8;
            bf16x8 bh = *(const bf16x8*)(B1h + bo);
            bf16x8 bl = *(const bf16x8*)(B1l + bo);
            acc0 = __builtin_amdgcn_mfma_f32_16x16x32_bf16(a0, bh, acc0, 0, 0, 0);
            acc0 = __builtin_amdgcn_mfma_f32_16x16x32_bf16(a0, bl, acc0, 0, 0, 0);
            acc1 = __builtin_amdgcn_mfma_f32_16x16x32_bf16(a1, bh, acc1, 0, 0, 0);
            acc1 = __builtin_amdgcn_mfma_f32_16x16x32_bf16(a1, bl, acc1, 0, 0, 0);
        }
    };

    // ---- fused layer1(TS part) || gather pipeline ----
    if (nfull > 0) issue8(i40);
    kk4(0);
    if (nfull > 0) acc8();
    if (nfull > 1) issue8(i41);
    kk4(4);
    if (nfull > 1) acc8();
    if (nfull > 2) issue8(i42);
    kk4(8);
    if (nfull > 2) acc8();
    if (nfull > 3) issue8(i43);
    kk4(12);
    if (nfull > 3) acc8();
    for (int b = 4; b < nfull; ++b) {           // residual full batches (c>32)
        uint4 i4 = *(const uint4*)(crow + b * 8);
        issue8(i4);
        acc8();
    }
    {
        int j = nfull * 8;
        if (j < c) {                            // predicated partial tail
            uint4 i4 = *(const uint4*)(crow + j);  // slots j..j+7 < 96
            u32 w[4] = {i4.x, i4.y, i4.z, i4.w};
#pragma unroll
            for (int k = 0; k < 8; ++k) {
                int s = (int)((w[k >> 1] >> ((k & 1) * 16)) & 0xffffu);
                bool live = (j + k) < c;
                s = live ? s : 0;               // garbage slots never derefed
                uint4 p = GHLoad(s);
                if (live) ACC(p);
            }
        }
    }
#undef ACC

    // ---- SAG store (agg hi/lo) ----
    {
        float inv = (ctrue > 0) ? 1.f / (float)ctrue : 0.f;
        int base = (gr * 136 + cg * 8) >> 1;   // u32 index (even)
        u32* SH = (u32*)SAGh;
        u32* SL = (u32*)SAGl;
#pragma unroll
        for (int p = 0; p < 4; ++p) {
            float x = a[2 * p] * inv, y = a[2 * p + 1] * inv;
            u16 hx = f2b(x), hy = f2b(y);
            SH[base + p] = (u32)hx | ((u32)hy << 16);
            SL[base + p] = (u32)f2b(x - b2f(hx)) | ((u32)f2b(y - b2f(hy)) << 16);
        }
    }
    __syncthreads();   // SAG ready; also: all TS reads complete before this

    // ---- layer1 agg part: kk16..19 from SAG ----
#pragma unroll
    for (int kk = 16; kk < 20; ++kk) {
        int o = (kk - 16) * 32;
        bf16x8 ah0 = *(const bf16x8*)(SAGh + hr0 + o);
        bf16x8 al0 = *(const bf16x8*)(SAGl + hr0 + o);
        bf16x8 ah1 = *(const bf16x8*)(SAGh + hr1 + o);
        bf16x8 al1 = *(const bf16x8*)(SAGl + hr1 + o);
        size_t bo = ((size_t)(kk * 8 + g) * 64 + lane) * 8;
        bf16x8 bh = *(const bf16x8*)(B1h + bo);
        bf16x8 bl = *(const bf16x8*)(B1l + bo);
        acc0 = __builtin_amdgcn_mfma_f32_16x16x32_bf16(ah0, bh, acc0, 0, 0, 0);
        acc0 = __builtin_amdgcn_mfma_f32_16x16x32_bf16(ah0, bl, acc0, 0, 0, 0);
        acc0 = __builtin_amdgcn_mfma_f32_16x16x32_bf16(al0, bh, acc0, 0, 0, 0);
        acc1 = __builtin_amdgcn_mfma_f32_16x16x32_bf16(ah1, bh, acc1, 0, 0, 0);
        acc1 = __builtin_amdgcn_mfma_f32_16x16x32_bf16(ah1, bl, acc1, 0, 0, 0);
        acc1 = __builtin_amdgcn_mfma_f32_16x16x32_bf16(al1, bh, acc1, 0, 0, 0);
    }
    // S1 write overlays TS: safe — every wave's TS reads precede the barrier
    {
        int n = g * 16 + n16;
        float bias = b1[n];
#pragma unroll
        for (int rg = 0; rg < 4; ++rg) {
            float v0 = acc0[rg] + bias; v0 = v0 > 0.f ? v0 : 0.f;
            float v1 = acc1[rg] + bias; v1 = v1 > 0.f ? v1 : 0.f;
            u16 h0 = f2b(v0), h1v = f2b(v1);
            S1h[(cr0 + rg) * 136 + n] = h0; S1l[(cr0 + rg) * 136 + n] = f2b(v0 - b2f(h0));
            S1h[(cr1 + rg) * 136 + n] = h1v; S1l[(cr1 + rg) * 136 + n] = f2b(v1 - b2f(h1v));
        }
    }
    __syncthreads();

    // ---- layer2: K=256 (h1 kk0..3 S1; agg kk4..7 SAG) ----
    acc0 = z4; acc1 = z4;
#pragma unroll
    for (int kk = 0; kk < 8; ++kk) {
        const u16* Ph = (kk < 4) ? S1h : SAGh;
        const u16* Pl = (kk < 4) ? S1l : SAGl;
        int o = (kk & 3) * 32;
        bf16x8 ah0 = *(const bf16x8*)(Ph + hr0 + o);
        bf16x8 al0 = *(const bf16x8*)(Pl + hr0 + o);
        bf16x8 ah1 = *(const bf16x8*)(Ph + hr1 + o);
        bf16x8 al1 = *(const bf16x8*)(Pl + hr1 + o);
        size_t bo = ((size_t)(kk * 8 + g) * 64 + lane) * 8;
        bf16x8 bh = *(const bf16x8*)(B2h + bo);
        bf16x8 bl = *(const bf16x8*)(B2l + bo);
        acc0 = __builtin_amdgcn_mfma_f32_16x16x32_bf16(ah0, bh, acc0, 0, 0, 0);
        acc0 = __builtin_amdgcn_mfma_f32_16x16x32_bf16(ah0, bl, acc0, 0, 0, 0);
        acc0 = __builtin_amdgcn_mfma_f32_16x16x32_bf16(al0, bh, acc0, 0, 0, 0);
        acc1 = __builtin_amdgcn_mfma_f32_16x16x32_bf16(ah1, bh, acc1, 0, 0, 0);
        acc1 = __builtin_amdgcn_mfma_f32_16x16x32_bf16(ah1, bl, acc1, 0, 0, 0);
        acc1 = __builtin_amdgcn_mfma_f32_16x16x32_bf16(al1, bh, acc1, 0, 0, 0);
    }
    {
        int n = g * 16 + n16;
        float bias = b2[n];
#pragma unroll
        for (int rg = 0; rg < 4; ++rg) {
            float v0 = acc0[rg] + bias; v0 = v0 > 0.f ? v0 : 0.f;
            float v1 = acc1[rg] + bias; v1 = v1 > 0.f ? v1 : 0.f;
            u16 h0 = f2b(v0), h1v = f2b(v1);
            S2h[(cr0 + rg) * 136 + n] = h0; S2l[(cr0 + rg) * 136 + n] = f2b(v0 - b2f(h0));
            S2h[(cr1 + rg) * 136 + n] = h1v; S2l[(cr1 + rg) * 136 + n] = f2b(v1 - b2f(h1v));
        }
    }
    __syncthreads();

    // ---- layer3: K=128 (h2 S2) -> S1 ----
    acc0 = z4; acc1 = z4;
#pragma unroll
    for (int kk = 0; kk < 4; ++kk) {
        int o = kk * 32;
        bf16x8 ah0 = *(const bf16x8*)(S2h + hr0 + o);
        bf16x8 al0 = *(const bf16x8*)(S2l + hr0 + o);
        bf16x8 ah1 = *(const bf16x8*)(S2h + hr1 + o);
        bf16x8 al1 = *(const bf16x8*)(S2l + hr1 + o);
        size_t bo = ((size_t)(kk * 8 + g) * 64 + lane) * 8;
        bf16x8 bh = *(const bf16x8*)(B3h + bo);
        bf16x8 bl = *(const bf16x8*)(B3l + bo);
        acc0 = __builtin_amdgcn_mfma_f32_16x16x32_bf16(ah0, bh, acc0, 0, 0, 0);
        acc0 = __builtin_amdgcn_mfma_f32_16x16x32_bf16(ah0, bl, acc0, 0, 0, 0);
        acc0 = __builtin_amdgcn_mfma_f32_16x16x32_bf16(al0, bh, acc0, 0, 0, 0);
        acc1 = __builtin_amdgcn_mfma_f32_16x16x32_bf16(ah1, bh, acc1, 0, 0, 0);
        acc1 = __builtin_amdgcn_mfma_f32_16x16x32_bf16(ah1, bl, acc1, 0, 0, 0);
        acc1 = __builtin_amdgcn_mfma_f32_16x16x32_bf16(al1, bh, acc1, 0, 0, 0);
    }
    {
        int n = g * 16 + n16;
        float bias = bc1[n];
#pragma unroll
        for (int rg = 0; rg < 4; ++rg) {
            float v0 = acc0[rg] + bias; v0 = v0 > 0.f ? v0 : 0.f;
            float v1 = acc1[rg] + bias; v1 = v1 > 0.f ? v1 : 0.f;
            u16 h0 = f2b(v0), h1v = f2b(v1);
            S1h[(cr0 + rg) * 136 + n] = h0; S1l[(cr0 + rg) * 136 + n] = f2b(v0 - b2f(h0));
            S1h[(cr1 + rg) * 136 + n] = h1v; S1l[(cr1 + rg) * 136 + n] = f2b(v1 - b2f(h1v));
        }
    }
    __syncthreads();

    // ---- layer4: K=128, N=16 (waves 0,1 = tiles 0,1) ----
    if (g < 2) {
        int hr = (g == 0) ? hr0 : hr1;
        int cr = (g == 0) ? cr0 : cr1;
        f32x4 a4 = z4;
#pragma unroll
        for (int kk = 0; kk < 4; ++kk) {
            bf16x8 ah = *(const bf16x8*)(S1h + hr + kk * 32);
            bf16x8 al = *(const bf16x8*)(S1l + hr + kk * 32);
            size_t bo = ((size_t)kk * 64 + lane) * 8;
            bf16x8 bh = *(const bf16x8*)(B4h + bo);
            bf16x8 bl = *(const bf16x8*)(B4l + bo);
            a4 = __builtin_amdgcn_mfma_f32_16x16x32_bf16(ah, bh, a4, 0, 0, 0);
            a4 = __builtin_amdgcn_mfma_f32_16x16x32_bf16(ah, bl, a4, 0, 0, 0);
            a4 = __builtin_amdgcn_mfma_f32_16x16x32_bf16(al, bh, a4, 0, 0, 0);
        }
        float bias = bc2[n16];
#pragma unroll
        for (int rg = 0; rg < 4; ++rg)
            out[(size_t)(row0 + cr + rg) * NCLS + n16] = a4[rg] + bias;
    }
}

extern "C" void kernel_launch(void* const* d_in, const int* in_sizes, int n_in,
                              void* d_out, int out_size, void* d_ws, size_t ws_size,
                              hipStream_t stream) {
    const float* gene = (const float*)d_in[0];
    const float* train = (const float*)d_in[1];
    const int* esrc = (const int*)d_in[2];
    const int* edst = (const int*)d_in[3];

    char* ws = (char*)d_ws;
    int* bcnt = (int*)(ws + 0);             //     2500 (pad to 4096)
    u32* bkt = (u32*)(ws + 4096);           //  3840000 (625*1536*4)
    u16* GH = (u16*)(ws + 3844096);         //   640000 (2500*128 u16)
    u16* B1h = (u16*)(ws + 4484096);        //   163840
    u16* B1l = (u16*)(ws + 4647936);        //   163840
    u16* B2h = (u16*)(ws + 4811776);        //    65536
    u16* B2l = (u16*)(ws + 4877312);        //    65536
    u16* B3h = (u16*)(ws + 4942848);        //    32768
    u16* B3l = (u16*)(ws + 4975616);        //    32768
    u16* B4h = (u16*)(ws + 5008384);        //     4096
    u16* B4l = (u16*)(ws + 5012480);        //     4096
    // total 5,016,576 B

    hipMemsetAsync(bcnt, 0, NEB * sizeof(int), stream);
    k_prep<<<NEB + GNB + PKB, 256, 0, stream>>>(
        esrc, edst, bcnt, bkt, gene, (u32*)GH,
        (const float*)d_in[4], (const float*)d_in[5], (const float*)d_in[7],
        (const float*)d_in[8], (const float*)d_in[10], (const float*)d_in[12],
        B1h, B1l, B2h, B2l, B3h, B3l, B4h, B4l);
    k_mega<<<NT / 32, 512, 0, stream>>>(
        bcnt, bkt, GH, train, B1h, B1l, B2h, B2l, B3h, B3l, B4h, B4l,
        (const float*)d_in[6], (const float*)d_in[9], (const float*)d_in[11],
        (const float*)d_in[13], (float*)d_out);
}

// Round 10
// 155.093 us; speedup vs baseline: 2.0184x; 2.0184x over previous
//
#include <hip/hip_runtime.h>

// WordSAGE on MI355X — fp32 in/out. Round-20 (4 kernels, no memset):
// r9 lesson: 640K returning atomicAdds on 625 counters serialize (174us).
// r7/r0 lesson: per-dst scatter is atomic-transaction-throughput-bound
// (~50us at any occupancy). Fix: NO global atomics at all.
//   k_prep (P1): per-block LDS hist over 625 dst-buckets -> hist[block][bin]
//                coalesced; + gene->GH + weight pack (same grid).
//   k_scan (P2): one block per bin: exclusive scan of hist[*][bin] over the
//                625 blocks (LDS Hillis-Steele) -> boff[bin][block], bcnt.
//   k_scat (P3): re-read edges, intra-block rank via LDS atomic, plain
//                store to bkt[bin][boff+rank]. Fire-and-forget.
//   k_mega     : VERBATIM r9 body (correctness-verified consumer).
// Precision: weights/agg/h split hi+lo bf16; train & gene hi-only (RNE).

#define NG 2500
#define NT 20000
#define NE 640000
#define NCLS 16
#define CAP 96
#define BCAP 1536   // bucket capacity (mean 1024, ~16 sigma headroom)
#define NBIN 625

typedef unsigned short u16;
typedef unsigned int u32;

typedef float f32x4 __attribute__((ext_vector_type(4)));
typedef __bf16 bf16x8 __attribute__((ext_vector_type(8)));

__device__ __forceinline__ float b2f(u16 u) { return __uint_as_float(((u32)u) << 16); }
__device__ __forceinline__ float blo(u32 p) { return __uint_as_float(p << 16); }
__device__ __forceinline__ float bhi(u32 p) { return __uint_as_float(p & 0xffff0000u); }
__device__ __forceinline__ u16 f2b(float f) {  // RNE fp32->bf16
    u32 u = __float_as_uint(f);
    return (u16)((u + 0x7fffu + ((u >> 16) & 1u)) >> 16);
}

// ---- sizes ---------------------------------------------------------------
#define B1N 81920   // K=640: train k 0..499, zero 500..511, agg 512..639; N=128
#define B2N 32768   // K=256: h1 (W2s) 0..127, agg (W2n) 128..255; N=128
#define B3N 16384   // K=128 Wc1, N=128
#define B4N 2048    // K=128 Wc2, N=16
#define NEB 625     // edge blocks (4 edges/thread)
#define GNB 625     // gene-convert blocks
#define PKB 520     // pack blocks

// ---- P1: hist + gene convert + weight pack --------------------------------
__global__ __launch_bounds__(256) void k_prep(
    const int* __restrict__ edst,
    u32* __restrict__ hist,
    const float* __restrict__ gene, u32* __restrict__ GH32,
    const float* __restrict__ W1n, const float* __restrict__ W1s,
    const float* __restrict__ W2n, const float* __restrict__ W2s,
    const float* __restrict__ Wc1, const float* __restrict__ Wc2,
    u16* __restrict__ B1h, u16* __restrict__ B1l,
    u16* __restrict__ B2h, u16* __restrict__ B2l,
    u16* __restrict__ B3h, u16* __restrict__ B3l,
    u16* __restrict__ B4h, u16* __restrict__ B4l) {
    int blk = blockIdx.x, t = threadIdx.x;
    if (blk < NEB) {
        __shared__ u32 lh[NBIN];
        for (int i = t; i < NBIN; i += 256) lh[i] = 0;
        __syncthreads();
        int e0 = (blk * 256 + t) * 4;
        const int4 d4 = *(const int4*)(edst + e0);
        int dd[4] = {d4.x, d4.y, d4.z, d4.w};
#pragma unroll
        for (int i = 0; i < 4; ++i) {
            unsigned d = (unsigned)dd[i];
            if (d < NT) atomicAdd(&lh[d >> 5], 1u);   // LDS atomic — cheap
        }
        __syncthreads();
        for (int i = t; i < NBIN; i += 256)
            hist[(size_t)blk * NBIN + i] = lh[i];     // coalesced
        return;
    }
    if (blk < NEB + GNB) {
        int idx = (blk - NEB) * 256 + t;  // < 160000
        float2 v = ((const float2*)gene)[idx];
        GH32[idx] = (u32)f2b(v.x) | ((u32)f2b(v.y) << 16);
        return;
    }
    // ---- weight pack (split hi/lo, B-fragment order) ----
    int idx = (blk - NEB - GNB) * 256 + t;
    float v = 0.f;
    u16 *ph = 0, *pl = 0;
    int off = 0;
    if (idx < B1N) {
        int j = idx & 7, l = (idx >> 3) & 63, rest = idx >> 9;
        int g = rest & 7, kk = rest >> 3;
        int k = kk * 32 + ((l >> 4) << 3) + j, n = (g << 4) + (l & 15);
        if (k < 500) v = W1s[k * 128 + n];
        else if (k >= 512) v = W1n[(k - 512) * 128 + n];
        ph = B1h; pl = B1l; off = idx;
    } else if (idx < B1N + B2N) {
        int e = idx - B1N;
        int j = e & 7, l = (e >> 3) & 63, rest = e >> 9;
        int g = rest & 7, kk = rest >> 3;
        int k = kk * 32 + ((l >> 4) << 3) + j, n = (g << 4) + (l & 15);
        v = (k < 128) ? W2s[k * 128 + n] : W2n[(k - 128) * 128 + n];
        ph = B2h; pl = B2l; off = e;
    } else if (idx < B1N + B2N + B3N) {
        int e = idx - (B1N + B2N);
        int j = e & 7, l = (e >> 3) & 63, rest = e >> 9;
        int g = rest & 7, kk = rest >> 3;
        int k = kk * 32 + ((l >> 4) << 3) + j, n = (g << 4) + (l & 15);
        v = Wc1[k * 128 + n];
        ph = B3h; pl = B3l; off = e;
    } else if (idx < B1N + B2N + B3N + B4N) {
        int e = idx - (B1N + B2N + B3N);
        int j = e & 7, l = (e >> 3) & 63, kk = e >> 9;
        int k = kk * 32 + ((l >> 4) << 3) + j, n = l & 15;
        v = Wc2[k * 16 + n];
        ph = B4h; pl = B4l; off = e;
    }
    if (ph) {
        u16 hi = f2b(v);
        u16 lo = f2b(v - b2f(hi));
        ph[off] = hi;
        pl[off] = lo;
    }
}

// ---- P2: per-bin exclusive scan over blocks -------------------------------
__global__ __launch_bounds__(256) void k_scan(
    const u32* __restrict__ hist, u32* __restrict__ boff,
    int* __restrict__ bcnt) {
    int bin = blockIdx.x, t = threadIdx.x;
    __shared__ u32 part[256];
    u32 s0 = 0, s1 = 0, s2 = 0;
    int i0 = 3 * t;
    if (i0 < NBIN) s0 = hist[(size_t)i0 * NBIN + bin];
    if (i0 + 1 < NBIN) s1 = hist[(size_t)(i0 + 1) * NBIN + bin];
    if (i0 + 2 < NBIN) s2 = hist[(size_t)(i0 + 2) * NBIN + bin];
    u32 mine = s0 + s1 + s2;
    part[t] = mine;
    __syncthreads();
    for (int off = 1; off < 256; off <<= 1) {   // Hillis-Steele inclusive
        u32 x = (t >= off) ? part[t - off] : 0u;
        __syncthreads();
        part[t] += x;
        __syncthreads();
    }
    u32 base = part[t] - mine;                  // exclusive prefix
    if (i0 < NBIN) boff[(size_t)bin * NBIN + i0] = base;
    if (i0 + 1 < NBIN) boff[(size_t)bin * NBIN + i0 + 1] = base + s0;
    if (i0 + 2 < NBIN) boff[(size_t)bin * NBIN + i0 + 2] = base + s0 + s1;
    if (t == 255) bcnt[bin] = (int)part[255];
}

// ---- P3: rank-and-place scatter (no global atomics) -----------------------
__global__ __launch_bounds__(256) void k_scat(
    const int* __restrict__ esrc, const int* __restrict__ edst,
    const u32* __restrict__ boff, u32* __restrict__ bkt) {
    int blk = blockIdx.x, t = threadIdx.x;
    __shared__ u32 lcur[NBIN];
    for (int i = t; i < NBIN; i += 256) lcur[i] = 0;
    __syncthreads();
    int e0 = (blk * 256 + t) * 4;
    const int4 s4 = *(const int4*)(esrc + e0);
    const int4 d4 = *(const int4*)(edst + e0);
    int ss[4] = {s4.x, s4.y, s4.z, s4.w};
    int dd[4] = {d4.x, d4.y, d4.z, d4.w};
#pragma unroll
    for (int i = 0; i < 4; ++i) {
        unsigned d = (unsigned)dd[i];
        if (d < NT) {
            int bin = (int)(d >> 5);
            u32 rank = atomicAdd(&lcur[bin], 1u);           // LDS atomic
            u32 pos = boff[(size_t)bin * NBIN + blk] + rank;
            if (pos < BCAP)
                bkt[(size_t)bin * BCAP + pos] = ((d & 31u) << 16) | (u32)ss[i];
        }
    }
}

// ---- fused sort + gather + stage + 4-layer MFMA (VERBATIM r9) --------------
__global__ __launch_bounds__(512, 3) void k_mega(
    const int* __restrict__ bcnt, const u32* __restrict__ bkt,
    const u16* __restrict__ GH, const float* __restrict__ train,
    const u16* __restrict__ B1h, const u16* __restrict__ B1l,
    const u16* __restrict__ B2h, const u16* __restrict__ B2l,
    const u16* __restrict__ B3h, const u16* __restrict__ B3l,
    const u16* __restrict__ B4h, const u16* __restrict__ B4l,
    const float* __restrict__ b1, const float* __restrict__ b2,
    const float* __restrict__ bc1, const float* __restrict__ bc2,
    float* __restrict__ out) {
    __shared__ __align__(16) u16 SMEM[26112];   // 52224 B
    __shared__ __align__(16) u16 SRT[32 * CAP]; // 6144 B per-row lists
    __shared__ int POS[32];
    u16* SAGh = SMEM;
    u16* SAGl = SMEM + 4352;
    u16* S1h = SMEM + 8704;
    u16* S1l = SMEM + 13056;
    u16* S2h = SMEM + 17408;
    u16* S2l = SMEM + 21760;
    u16* TS = SMEM + 8704;                      // overlays S1h..S2l

    int t = threadIdx.x;
    int row0 = blockIdx.x * 32;

    // ---- phase 0a: issue train-tile loads (latency hides under sort) ----
    float4 st[8];
    {
        const float4* tb = (const float4*)(train + (size_t)row0 * 500);
#pragma unroll
        for (int i = 0; i < 7; ++i) st[i] = tb[t + i * 512];
        if (t < 416) st[7] = tb[t + 3584];      // 4000 float4 = 32 rows x 125
    }

    if (t < 32) POS[t] = 0;
    int bc = bcnt[blockIdx.x];
    if (bc > BCAP) bc = BCAP;
    __syncthreads();

    // ---- phase 0b: counting-scatter bucket -> per-row LDS CSR ----
    for (int i = t; i < bc; i += 512) {
        u32 e = bkt[(size_t)blockIdx.x * BCAP + i];  // coalesced
        int r = (int)(e >> 16);
        int p = atomicAdd(&POS[r], 1);
        if (p < CAP) SRT[r * CAP + p] = (u16)(e & 0xffffu);
    }

    // ---- phase 0c: convert staged tile -> TS (row-major [32][520] bf16) ----
    {
        u32* T32 = (u32*)TS;
#pragma unroll
        for (int i = 0; i < 8; ++i) {
            int idx = t + i * 512;
            if (i == 7 && t >= 416) break;
            int r = idx / 125, c4 = idx - r * 125;
            int base = r * 260 + c4 * 2;       // u32 units; row stride 520 u16
            T32[base] = (u32)f2b(st[i].x) | ((u32)f2b(st[i].y) << 16);
            T32[base + 1] = (u32)f2b(st[i].z) | ((u32)f2b(st[i].w) << 16);
        }
        if (t < 192) {                          // zero cols 500..511
            int r = t / 6, c4 = t - r * 6;
            T32[r * 260 + 250 + c4] = 0;
        }
    }
    __syncthreads();   // SRT + POS + TS ready

    int lane = t & 63, g = t >> 6;  // wave index = col-group 0..7
    int m = lane & 15, q = lane >> 4, n16 = lane & 15;
    int gr = t >> 4, cg = t & 15;   // gather row 0..31, col-group 0..15

    int ctrue = POS[gr];
    int c = ctrue > CAP ? CAP : ctrue;
    const u16* crow = SRT + gr * CAP;
    int nfull = c >> 3;
    uint4 i40 = *(const uint4*)(crow);          // LDS, 16-lane broadcast
    uint4 i41 = *(const uint4*)(crow + 8);
    uint4 i42 = *(const uint4*)(crow + 16);
    uint4 i43 = *(const uint4*)(crow + 24);
    float a[8];
#pragma unroll
    for (int p = 0; p < 8; ++p) a[p] = 0.f;

    int hr0 = m * 136 + q * 8;
    int hr1 = (16 + m) * 136 + q * 8;
    int cr0 = q * 4, cr1 = 16 + q * 4;
    const f32x4 z4 = {0.f, 0.f, 0.f, 0.f};
    f32x4 acc0 = z4, acc1 = z4;
    const u16* tA0 = TS + m * 520 + q * 8;
    const u16* tA1 = TS + (16 + m) * 520 + q * 8;

#define ACC(p)                                      \
    do {                                            \
        a[0] += blo((p).x); a[1] += bhi((p).x);     \
        a[2] += blo((p).y); a[3] += bhi((p).y);     \
        a[4] += blo((p).z); a[5] += bhi((p).z);     \
        a[6] += blo((p).w); a[7] += bhi((p).w);     \
    } while (0)

    auto GHLoad = [&](int s) -> uint4 {
        return *(const uint4*)(GH + (size_t)s * 128 + cg * 8);
    };
    uint4 P0, P1, P2, P3, P4, P5, P6, P7;
    auto issue8 = [&](uint4 iq) {
        P0 = GHLoad((int)(iq.x & 0xffffu)); P1 = GHLoad((int)(iq.x >> 16));
        P2 = GHLoad((int)(iq.y & 0xffffu)); P3 = GHLoad((int)(iq.y >> 16));
        P4 = GHLoad((int)(iq.z & 0xffffu)); P5 = GHLoad((int)(iq.z >> 16));
        P6 = GHLoad((int)(iq.w & 0xffffu)); P7 = GHLoad((int)(iq.w >> 16));
    };
    auto acc8 = [&]() {
        ACC(P0); ACC(P1); ACC(P2); ACC(P3);
        ACC(P4); ACC(P5); ACC(P6); ACC(P7);
    };
    auto kk4 = [&](int base) {
#pragma unroll
        for (int kk = base; kk < base + 4; ++kk) {
            bf16x8 a0 = *(const bf16x8*)(tA0 + kk * 32);
            bf16x8 a1 = *(const bf16x8*)(tA1 + kk * 32);
            size_t bo = ((size_t)(kk * 8 + g) * 64 + lane) * 8;
            bf16x8 bh = *(const bf16x8*)(B1h + bo);
            bf16x8 bl = *(const bf16x8*)(B1l + bo);
            acc0 = __builtin_amdgcn_mfma_f32_16x16x32_bf16(a0, bh, acc0, 0, 0, 0);
            acc0 = __builtin_amdgcn_mfma_f32_16x16x32_bf16(a0, bl, acc0, 0, 0, 0);
            acc1 = __builtin_amdgcn_mfma_f32_16x16x32_bf16(a1, bh, acc1, 0, 0, 0);
            acc1 = __builtin_amdgcn_mfma_f32_16x16x32_bf16(a1, bl, acc1, 0, 0, 0);
        }
    };

    // ---- fused layer1(TS part) || gather pipeline ----
    if (nfull > 0) issue8(i40);
    kk4(0);
    if (nfull > 0) acc8();
    if (nfull > 1) issue8(i41);
    kk4(4);
    if (nfull > 1) acc8();
    if (nfull > 2) issue8(i42);
    kk4(8);
    if (nfull > 2) acc8();
    if (nfull > 3) issue8(i43);
    kk4(12);
    if (nfull > 3) acc8();
    for (int b = 4; b < nfull; ++b) {           // residual full batches (c>32)
        uint4 i4 = *(const uint4*)(crow + b * 8);
        issue8(i4);
        acc8();
    }
    {
        int j = nfull * 8;
        if (j < c) {                            // predicated partial tail
            uint4 i4 = *(const uint4*)(crow + j);  // slots j..j+7 < 96
            u32 w[4] = {i4.x, i4.y, i4.z, i4.w};
#pragma unroll
            for (int k = 0; k < 8; ++k) {
                int s = (int)((w[k >> 1] >> ((k & 1) * 16)) & 0xffffu);
                bool live = (j + k) < c;
                s = live ? s : 0;               // garbage slots never derefed
                uint4 p = GHLoad(s);
                if (live) ACC(p);
            }
        }
    }
#undef ACC

    // ---- SAG store (agg hi/lo) ----
    {
        float inv = (ctrue > 0) ? 1.f / (float)ctrue : 0.f;
        int base = (gr * 136 + cg * 8) >> 1;   // u32 index (even)
        u32* SH = (u32*)SAGh;
        u32* SL = (u32*)SAGl;
#pragma unroll
        for (int p = 0; p < 4; ++p) {
            float x = a[2 * p] * inv, y = a[2 * p + 1] * inv;
            u16 hx = f2b(x), hy = f2b(y);
            SH[base + p] = (u32)hx | ((u32)hy << 16);
            SL[base + p] = (u32)f2b(x - b2f(hx)) | ((u32)f2b(y - b2f(hy)) << 16);
        }
    }
    __syncthreads();   // SAG ready; also: all TS reads complete before this

    // ---- layer1 agg part: kk16..19 from SAG ----
#pragma unroll
    for (int kk = 16; kk < 20; ++kk) {
        int o = (kk - 16) * 32;
        bf16x8 ah0 = *(const bf16x8*)(SAGh + hr0 + o);
        bf16x8 al0 = *(const bf16x8*)(SAGl + hr0 + o);
        bf16x8 ah1 = *(const bf16x8*)(SAGh + hr1 + o);
        bf16x8 al1 = *(const bf16x8*)(SAGl + hr1 + o);
        size_t bo = ((size_t)(kk * 8 + g) * 64 + lane) * 8;
        bf16x8 bh = *(const bf16x8*)(B1h + bo);
        bf16x8 bl = *(const bf16x8*)(B1l + bo);
        acc0 = __builtin_amdgcn_mfma_f32_16x16x32_bf16(ah0, bh, acc0, 0, 0, 0);
        acc0 = __builtin_amdgcn_mfma_f32_16x16x32_bf16(ah0, bl, acc0, 0, 0, 0);
        acc0 = __builtin_amdgcn_mfma_f32_16x16x32_bf16(al0, bh, acc0, 0, 0, 0);
        acc1 = __builtin_amdgcn_mfma_f32_16x16x32_bf16(ah1, bh, acc1, 0, 0, 0);
        acc1 = __builtin_amdgcn_mfma_f32_16x16x32_bf16(ah1, bl, acc1, 0, 0, 0);
        acc1 = __builtin_amdgcn_mfma_f32_16x16x32_bf16(al1, bh, acc1, 0, 0, 0);
    }
    // S1 write overlays TS: safe — every wave's TS reads precede the barrier
    {
        int n = g * 16 + n16;
        float bias = b1[n];
#pragma unroll
        for (int rg = 0; rg < 4; ++rg) {
            float v0 = acc0[rg] + bias; v0 = v0 > 0.f ? v0 : 0.f;
            float v1 = acc1[rg] + bias; v1 = v1 > 0.f ? v1 : 0.f;
            u16 h0 = f2b(v0), h1v = f2b(v1);
            S1h[(cr0 + rg) * 136 + n] = h0; S1l[(cr0 + rg) * 136 + n] = f2b(v0 - b2f(h0));
            S1h[(cr1 + rg) * 136 + n] = h1v; S1l[(cr1 + rg) * 136 + n] = f2b(v1 - b2f(h1v));
        }
    }
    __syncthreads();

    // ---- layer2: K=256 (h1 kk0..3 S1; agg kk4..7 SAG) ----
    acc0 = z4; acc1 = z4;
#pragma unroll
    for (int kk = 0; kk < 8; ++kk) {
        const u16* Ph = (kk < 4) ? S1h : SAGh;
        const u16* Pl = (kk < 4) ? S1l : SAGl;
        int o = (kk & 3) * 32;
        bf16x8 ah0 = *(const bf16x8*)(Ph + hr0 + o);
        bf16x8 al0 = *(const bf16x8*)(Pl + hr0 + o);
        bf16x8 ah1 = *(const bf16x8*)(Ph + hr1 + o);
        bf16x8 al1 = *(const bf16x8*)(Pl + hr1 + o);
        size_t bo = ((size_t)(kk * 8 + g) * 64 + lane) * 8;
        bf16x8 bh = *(const bf16x8*)(B2h + bo);
        bf16x8 bl = *(const bf16x8*)(B2l + bo);
        acc0 = __builtin_amdgcn_mfma_f32_16x16x32_bf16(ah0, bh, acc0, 0, 0, 0);
        acc0 = __builtin_amdgcn_mfma_f32_16x16x32_bf16(ah0, bl, acc0, 0, 0, 0);
        acc0 = __builtin_amdgcn_mfma_f32_16x16x32_bf16(al0, bh, acc0, 0, 0, 0);
        acc1 = __builtin_amdgcn_mfma_f32_16x16x32_bf16(ah1, bh, acc1, 0, 0, 0);
        acc1 = __builtin_amdgcn_mfma_f32_16x16x32_bf16(ah1, bl, acc1, 0, 0, 0);
        acc1 = __builtin_amdgcn_mfma_f32_16x16x32_bf16(al1, bh, acc1, 0, 0, 0);
    }
    {
        int n = g * 16 + n16;
        float bias = b2[n];
#pragma unroll
        for (int rg = 0; rg < 4; ++rg) {
            float v0 = acc0[rg] + bias; v0 = v0 > 0.f ? v0 : 0.f;
            float v1 = acc1[rg] + bias; v1 = v1 > 0.f ? v1 : 0.f;
            u16 h0 = f2b(v0), h1v = f2b(v1);
            S2h[(cr0 + rg) * 136 + n] = h0; S2l[(cr0 + rg) * 136 + n] = f2b(v0 - b2f(h0));
            S2h[(cr1 + rg) * 136 + n] = h1v; S2l[(cr1 + rg) * 136 + n] = f2b(v1 - b2f(h1v));
        }
    }
    __syncthreads();

    // ---- layer3: K=128 (h2 S2) -> S1 ----
    acc0 = z4; acc1 = z4;
#pragma unroll
    for (int kk = 0; kk < 4; ++kk) {
        int o = kk * 32;
        bf16x8 ah0 = *(const bf16x8*)(S2h + hr0 + o);
        bf16x8 al0 = *(const bf16x8*)(S2l + hr0 + o);
        bf16x8 ah1 = *(const bf16x8*)(S2h + hr1 + o);
        bf16x8 al1 = *(const bf16x8*)(S2l + hr1 + o);
        size_t bo = ((size_t)(kk * 8 + g) * 64 + lane) * 8;
        bf16x8 bh = *(const bf16x8*)(B3h + bo);
        bf16x8 bl = *(const bf16x8*)(B3l + bo);
        acc0 = __builtin_amdgcn_mfma_f32_16x16x32_bf16(ah0, bh, acc0, 0, 0, 0);
        acc0 = __builtin_amdgcn_mfma_f32_16x16x32_bf16(ah0, bl, acc0, 0, 0, 0);
        acc0 = __builtin_amdgcn_mfma_f32_16x16x32_bf16(al0, bh, acc0, 0, 0, 0);
        acc1 = __builtin_amdgcn_mfma_f32_16x16x32_bf16(ah1, bh, acc1, 0, 0, 0);
        acc1 = __builtin_amdgcn_mfma_f32_16x16x32_bf16(ah1, bl, acc1, 0, 0, 0);
        acc1 = __builtin_amdgcn_mfma_f32_16x16x32_bf16(al1, bh, acc1, 0, 0, 0);
    }
    {
        int n = g * 16 + n16;
        float bias = bc1[n];
#pragma unroll
        for (int rg = 0; rg < 4; ++rg) {
            float v0 = acc0[rg] + bias; v0 = v0 > 0.f ? v0 : 0.f;
            float v1 = acc1[rg] + bias; v1 = v1 > 0.f ? v1 : 0.f;
            u16 h0 = f2b(v0), h1v = f2b(v1);
            S1h[(cr0 + rg) * 136 + n] = h0; S1l[(cr0 + rg) * 136 + n] = f2b(v0 - b2f(h0));
            S1h[(cr1 + rg) * 136 + n] = h1v; S1l[(cr1 + rg) * 136 + n] = f2b(v1 - b2f(h1v));
        }
    }
    __syncthreads();

    // ---- layer4: K=128, N=16 (waves 0,1 = tiles 0,1) ----
    if (g < 2) {
        int hr = (g == 0) ? hr0 : hr1;
        int cr = (g == 0) ? cr0 : cr1;
        f32x4 a4 = z4;
#pragma unroll
        for (int kk = 0; kk < 4; ++kk) {
            bf16x8 ah = *(const bf16x8*)(S1h + hr + kk * 32);
            bf16x8 al = *(const bf16x8*)(S1l + hr + kk * 32);
            size_t bo = ((size_t)kk * 64 + lane) * 8;
            bf16x8 bh = *(const bf16x8*)(B4h + bo);
            bf16x8 bl = *(const bf16x8*)(B4l + bo);
            a4 = __builtin_amdgcn_mfma_f32_16x16x32_bf16(ah, bh, a4, 0, 0, 0);
            a4 = __builtin_amdgcn_mfma_f32_16x16x32_bf16(ah, bl, a4, 0, 0, 0);
            a4 = __builtin_amdgcn_mfma_f32_16x16x32_bf16(al, bh, a4, 0, 0, 0);
        }
        float bias = bc2[n16];
#pragma unroll
        for (int rg = 0; rg < 4; ++rg)
            out[(size_t)(row0 + cr + rg) * NCLS + n16] = a4[rg] + bias;
    }
}

extern "C" void kernel_launch(void* const* d_in, const int* in_sizes, int n_in,
                              void* d_out, int out_size, void* d_ws, size_t ws_size,
                              hipStream_t stream) {
    const float* gene = (const float*)d_in[0];
    const float* train = (const float*)d_in[1];
    const int* esrc = (const int*)d_in[2];
    const int* edst = (const int*)d_in[3];

    char* ws = (char*)d_ws;
    int* bcnt = (int*)(ws + 0);             //     2500 (pad 4096)
    u32* hist = (u32*)(ws + 4096);          //  1562500 (625*625*4)
    u32* boff = (u32*)(ws + 1566720);       //  1562500
    u32* bkt = (u32*)(ws + 3129344);        //  3840000 (625*1536*4)
    u16* GH = (u16*)(ws + 6969344);         //   640000 (2500*128 u16)
    u16* B1h = (u16*)(ws + 7609344);        //   163840
    u16* B1l = (u16*)(ws + 7773184);        //   163840
    u16* B2h = (u16*)(ws + 7937024);        //    65536
    u16* B2l = (u16*)(ws + 8002560);        //    65536
    u16* B3h = (u16*)(ws + 8068096);        //    32768
    u16* B3l = (u16*)(ws + 8100864);        //    32768
    u16* B4h = (u16*)(ws + 8133632);        //     4096
    u16* B4l = (u16*)(ws + 8137728);        //     4096
    // total 8,141,824 B; no memset needed (hist/boff/bcnt fully rewritten,
    // bkt[0, bcnt) fully written each iteration)

    k_prep<<<NEB + GNB + PKB, 256, 0, stream>>>(
        edst, hist, gene, (u32*)GH,
        (const float*)d_in[4], (const float*)d_in[5], (const float*)d_in[7],
        (const float*)d_in[8], (const float*)d_in[10], (const float*)d_in[12],
        B1h, B1l, B2h, B2l, B3h, B3l, B4h, B4l);
    k_scan<<<NBIN, 256, 0, stream>>>(hist, boff, bcnt);
    k_scat<<<NEB, 256, 0, stream>>>(esrc, edst, boff, bkt);
    k_mega<<<NT / 32, 512, 0, stream>>>(
        bcnt, bkt, GH, train, B1h, B1l, B2h, B2l, B3h, B3l, B4h, B4l,
        (const float*)d_in[6], (const float*)d_in[9], (const float*)d_in[11],
        (const float*)d_in[13], (float*)d_out);
}

// Round 11
// 152.254 us; speedup vs baseline: 2.0560x; 1.0186x over previous
//
#include <hip/hip_runtime.h>

// WordSAGE on MI355X — fp32 in/out. Round-21 (5 kernels, no memset):
// r10 analysis: fused gather||MFMA pinned at 44us because gather concurrency
// is capped by the MFMA side's LDS/VGPR (16 waves/CU; Little's law wants 3x).
// Split:
//   k_prep (P1): per-block LDS hist over 625 dst-buckets + gene->GH + pack.
//   k_scan (P2): per-bin exclusive scan -> boff, bcnt. No global atomics.
//   k_scat (P3): rank-and-place scatter -> bkt. Fire-and-forget stores.
//   k_agg      : 16 rows/block, 256 thr, ~3KB LDS, launch_bounds(256,8) ->
//                ~32 waves/CU; 8-deep batched GH gather; writes agg hi/lo
//                packed u32 to global (10MB).
//   k_mlp      : r10 k_mega minus gather (SAG filled by one coalesced uint4
//                load/thread). LDS 52224B -> 3 blocks/CU (24 waves).
// Precision: weights/agg/h split hi+lo bf16; train & gene hi-only (RNE).
// Per-thread accumulation order unchanged from r10 (passed, absmax 2^-7).

#define NG 2500
#define NT 20000
#define NE 640000
#define NCLS 16
#define CAP 96
#define BCAP 1536   // bucket capacity (mean 1024, ~16 sigma headroom)
#define NBIN 625

typedef unsigned short u16;
typedef unsigned int u32;

typedef float f32x4 __attribute__((ext_vector_type(4)));
typedef __bf16 bf16x8 __attribute__((ext_vector_type(8)));

__device__ __forceinline__ float b2f(u16 u) { return __uint_as_float(((u32)u) << 16); }
__device__ __forceinline__ float blo(u32 p) { return __uint_as_float(p << 16); }
__device__ __forceinline__ float bhi(u32 p) { return __uint_as_float(p & 0xffff0000u); }
__device__ __forceinline__ u16 f2b(float f) {  // RNE fp32->bf16
    u32 u = __float_as_uint(f);
    return (u16)((u + 0x7fffu + ((u >> 16) & 1u)) >> 16);
}

// ---- sizes ---------------------------------------------------------------
#define B1N 81920   // K=640: train k 0..499, zero 500..511, agg 512..639; N=128
#define B2N 32768   // K=256: h1 (W2s) 0..127, agg (W2n) 128..255; N=128
#define B3N 16384   // K=128 Wc1, N=128
#define B4N 2048    // K=128 Wc2, N=16
#define NEB 625     // edge blocks (4 edges/thread)
#define GNB 625     // gene-convert blocks
#define PKB 520     // pack blocks

// ---- P1: hist + gene convert + weight pack --------------------------------
__global__ __launch_bounds__(256) void k_prep(
    const int* __restrict__ edst,
    u32* __restrict__ hist,
    const float* __restrict__ gene, u32* __restrict__ GH32,
    const float* __restrict__ W1n, const float* __restrict__ W1s,
    const float* __restrict__ W2n, const float* __restrict__ W2s,
    const float* __restrict__ Wc1, const float* __restrict__ Wc2,
    u16* __restrict__ B1h, u16* __restrict__ B1l,
    u16* __restrict__ B2h, u16* __restrict__ B2l,
    u16* __restrict__ B3h, u16* __restrict__ B3l,
    u16* __restrict__ B4h, u16* __restrict__ B4l) {
    int blk = blockIdx.x, t = threadIdx.x;
    if (blk < NEB) {
        __shared__ u32 lh[NBIN];
        for (int i = t; i < NBIN; i += 256) lh[i] = 0;
        __syncthreads();
        int e0 = (blk * 256 + t) * 4;
        const int4 d4 = *(const int4*)(edst + e0);
        int dd[4] = {d4.x, d4.y, d4.z, d4.w};
#pragma unroll
        for (int i = 0; i < 4; ++i) {
            unsigned d = (unsigned)dd[i];
            if (d < NT) atomicAdd(&lh[d >> 5], 1u);   // LDS atomic — cheap
        }
        __syncthreads();
        for (int i = t; i < NBIN; i += 256)
            hist[(size_t)blk * NBIN + i] = lh[i];     // coalesced
        return;
    }
    if (blk < NEB + GNB) {
        int idx = (blk - NEB) * 256 + t;  // < 160000
        float2 v = ((const float2*)gene)[idx];
        GH32[idx] = (u32)f2b(v.x) | ((u32)f2b(v.y) << 16);
        return;
    }
    // ---- weight pack (split hi/lo, B-fragment order) ----
    int idx = (blk - NEB - GNB) * 256 + t;
    float v = 0.f;
    u16 *ph = 0, *pl = 0;
    int off = 0;
    if (idx < B1N) {
        int j = idx & 7, l = (idx >> 3) & 63, rest = idx >> 9;
        int g = rest & 7, kk = rest >> 3;
        int k = kk * 32 + ((l >> 4) << 3) + j, n = (g << 4) + (l & 15);
        if (k < 500) v = W1s[k * 128 + n];
        else if (k >= 512) v = W1n[(k - 512) * 128 + n];
        ph = B1h; pl = B1l; off = idx;
    } else if (idx < B1N + B2N) {
        int e = idx - B1N;
        int j = e & 7, l = (e >> 3) & 63, rest = e >> 9;
        int g = rest & 7, kk = rest >> 3;
        int k = kk * 32 + ((l >> 4) << 3) + j, n = (g << 4) + (l & 15);
        v = (k < 128) ? W2s[k * 128 + n] : W2n[(k - 128) * 128 + n];
        ph = B2h; pl = B2l; off = e;
    } else if (idx < B1N + B2N + B3N) {
        int e = idx - (B1N + B2N);
        int j = e & 7, l = (e >> 3) & 63, rest = e >> 9;
        int g = rest & 7, kk = rest >> 3;
        int k = kk * 32 + ((l >> 4) << 3) + j, n = (g << 4) + (l & 15);
        v = Wc1[k * 128 + n];
        ph = B3h; pl = B3l; off = e;
    } else if (idx < B1N + B2N + B3N + B4N) {
        int e = idx - (B1N + B2N + B3N);
        int j = e & 7, l = (e >> 3) & 63, kk = e >> 9;
        int k = kk * 32 + ((l >> 4) << 3) + j, n = l & 15;
        v = Wc2[k * 16 + n];
        ph = B4h; pl = B4l; off = e;
    }
    if (ph) {
        u16 hi = f2b(v);
        u16 lo = f2b(v - b2f(hi));
        ph[off] = hi;
        pl[off] = lo;
    }
}

// ---- P2: per-bin exclusive scan over blocks -------------------------------
__global__ __launch_bounds__(256) void k_scan(
    const u32* __restrict__ hist, u32* __restrict__ boff,
    int* __restrict__ bcnt) {
    int bin = blockIdx.x, t = threadIdx.x;
    __shared__ u32 part[256];
    u32 s0 = 0, s1 = 0, s2 = 0;
    int i0 = 3 * t;
    if (i0 < NBIN) s0 = hist[(size_t)i0 * NBIN + bin];
    if (i0 + 1 < NBIN) s1 = hist[(size_t)(i0 + 1) * NBIN + bin];
    if (i0 + 2 < NBIN) s2 = hist[(size_t)(i0 + 2) * NBIN + bin];
    u32 mine = s0 + s1 + s2;
    part[t] = mine;
    __syncthreads();
    for (int off = 1; off < 256; off <<= 1) {   // Hillis-Steele inclusive
        u32 x = (t >= off) ? part[t - off] : 0u;
        __syncthreads();
        part[t] += x;
        __syncthreads();
    }
    u32 base = part[t] - mine;                  // exclusive prefix
    if (i0 < NBIN) boff[(size_t)bin * NBIN + i0] = base;
    if (i0 + 1 < NBIN) boff[(size_t)bin * NBIN + i0 + 1] = base + s0;
    if (i0 + 2 < NBIN) boff[(size_t)bin * NBIN + i0 + 2] = base + s0 + s1;
    if (t == 255) bcnt[bin] = (int)part[255];
}

// ---- P3: rank-and-place scatter (no global atomics) -----------------------
__global__ __launch_bounds__(256) void k_scat(
    const int* __restrict__ esrc, const int* __restrict__ edst,
    const u32* __restrict__ boff, u32* __restrict__ bkt) {
    int blk = blockIdx.x, t = threadIdx.x;
    __shared__ u32 lcur[NBIN];
    for (int i = t; i < NBIN; i += 256) lcur[i] = 0;
    __syncthreads();
    int e0 = (blk * 256 + t) * 4;
    const int4 s4 = *(const int4*)(esrc + e0);
    const int4 d4 = *(const int4*)(edst + e0);
    int ss[4] = {s4.x, s4.y, s4.z, s4.w};
    int dd[4] = {d4.x, d4.y, d4.z, d4.w};
#pragma unroll
    for (int i = 0; i < 4; ++i) {
        unsigned d = (unsigned)dd[i];
        if (d < NT) {
            int bin = (int)(d >> 5);
            u32 rank = atomicAdd(&lcur[bin], 1u);           // LDS atomic
            u32 pos = boff[(size_t)bin * NBIN + blk] + rank;
            if (pos < BCAP)
                bkt[(size_t)bin * BCAP + pos] = ((d & 31u) << 16) | (u32)ss[i];
        }
    }
}

// ---- k_agg: dedicated gather-mean, tuned for latency hiding ---------------
// 16 rows/block, 256 thr (16 thr/row), tiny LDS -> ~32 waves/CU resident.
// Bucket blockIdx>>1, half blockIdx&1. Writes agg hi/lo packed u32.
__global__ __launch_bounds__(256, 8) void k_agg(
    const int* __restrict__ bcnt, const u32* __restrict__ bkt,
    const u16* __restrict__ GH,
    u32* __restrict__ AGH, u32* __restrict__ AGL) {
    __shared__ __align__(16) u16 SRT[16 * CAP];
    __shared__ int POS[16];
    int t = threadIdx.x;
    int bk = blockIdx.x >> 1, half = blockIdx.x & 1;

    if (t < 16) POS[t] = 0;
    int bc = bcnt[bk];
    if (bc > BCAP) bc = BCAP;
    __syncthreads();

    int rlo = half * 16;
    for (int i = t; i < bc; i += 256) {
        u32 e = bkt[(size_t)bk * BCAP + i];     // coalesced
        int r = (int)(e >> 16) - rlo;
        if ((unsigned)r < 16u) {
            int p = atomicAdd(&POS[r], 1);
            if (p < CAP) SRT[r * CAP + p] = (u16)(e & 0xffffu);
        }
    }
    __syncthreads();

    int gr = t >> 4, cg = t & 15;
    int ctrue = POS[gr];
    int c = ctrue > CAP ? CAP : ctrue;
    const u16* crow = SRT + gr * CAP;
    int nfull = c >> 3;
    uint4 i40 = *(const uint4*)(crow);
    uint4 i41 = *(const uint4*)(crow + 8);
    uint4 i42 = *(const uint4*)(crow + 16);
    uint4 i43 = *(const uint4*)(crow + 24);
    float a[8];
#pragma unroll
    for (int p = 0; p < 8; ++p) a[p] = 0.f;

#define ACC(p)                                      \
    do {                                            \
        a[0] += blo((p).x); a[1] += bhi((p).x);     \
        a[2] += blo((p).y); a[3] += bhi((p).y);     \
        a[4] += blo((p).z); a[5] += bhi((p).z);     \
        a[6] += blo((p).w); a[7] += bhi((p).w);     \
    } while (0)
    auto GHLoad = [&](int s) -> uint4 {
        return *(const uint4*)(GH + (size_t)s * 128 + cg * 8);
    };
    auto batch8 = [&](uint4 iq) {
        uint4 P0 = GHLoad((int)(iq.x & 0xffffu));
        uint4 P1 = GHLoad((int)(iq.x >> 16));
        uint4 P2 = GHLoad((int)(iq.y & 0xffffu));
        uint4 P3 = GHLoad((int)(iq.y >> 16));
        uint4 P4 = GHLoad((int)(iq.z & 0xffffu));
        uint4 P5 = GHLoad((int)(iq.z >> 16));
        uint4 P6 = GHLoad((int)(iq.w & 0xffffu));
        uint4 P7 = GHLoad((int)(iq.w >> 16));
        ACC(P0); ACC(P1); ACC(P2); ACC(P3);
        ACC(P4); ACC(P5); ACC(P6); ACC(P7);
    };

    if (nfull > 0) batch8(i40);
    if (nfull > 1) batch8(i41);
    if (nfull > 2) batch8(i42);
    if (nfull > 3) batch8(i43);
    for (int b = 4; b < nfull; ++b) batch8(*(const uint4*)(crow + b * 8));
    {
        int j = nfull * 8;
        if (j < c) {                            // predicated partial tail
            uint4 i4 = *(const uint4*)(crow + j);  // slots j..j+7 < 96
            u32 w[4] = {i4.x, i4.y, i4.z, i4.w};
#pragma unroll
            for (int k = 0; k < 8; ++k) {
                int s = (int)((w[k >> 1] >> ((k & 1) * 16)) & 0xffffu);
                bool live = (j + k) < c;
                s = live ? s : 0;               // garbage slots never derefed
                uint4 p = GHLoad(s);
                if (live) ACC(p);
            }
        }
    }
#undef ACC

    float inv = (ctrue > 0) ? 1.f / (float)ctrue : 0.f;
    size_t base = (size_t)(blockIdx.x * 16 + gr) * 64 + cg * 4;
#pragma unroll
    for (int p = 0; p < 4; ++p) {
        float x = a[2 * p] * inv, y = a[2 * p + 1] * inv;
        u16 hx = f2b(x), hy = f2b(y);
        AGH[base + p] = (u32)hx | ((u32)hy << 16);
        AGL[base + p] = (u32)f2b(x - b2f(hx)) | ((u32)f2b(y - b2f(hy)) << 16);
    }
}

// ---- k_mlp: stage + 4-layer MFMA (r10 k_mega minus gather) -----------------
// Block: 512 thr (8 waves), 32 rows (2 tiles). wave = col-group g (0..7).
// LDS 52224B -> 3 blocks/CU (24 waves). SAG filled from global agg.
__global__ __launch_bounds__(512, 4) void k_mlp(
    const u32* __restrict__ AGH, const u32* __restrict__ AGL,
    const float* __restrict__ train,
    const u16* __restrict__ B1h, const u16* __restrict__ B1l,
    const u16* __restrict__ B2h, const u16* __restrict__ B2l,
    const u16* __restrict__ B3h, const u16* __restrict__ B3l,
    const u16* __restrict__ B4h, const u16* __restrict__ B4l,
    const float* __restrict__ b1, const float* __restrict__ b2,
    const float* __restrict__ bc1, const float* __restrict__ bc2,
    float* __restrict__ out) {
    __shared__ __align__(16) u16 SMEM[26112];   // 52224 B
    u16* SAGh = SMEM;
    u16* SAGl = SMEM + 4352;
    u16* S1h = SMEM + 8704;
    u16* S1l = SMEM + 13056;
    u16* S2h = SMEM + 17408;
    u16* S2l = SMEM + 21760;
    u16* TS = SMEM + 8704;                      // overlays S1h..S2l

    int t = threadIdx.x;
    int row0 = blockIdx.x * 32;

    // ---- phase 0a: issue train + agg loads (latency overlaps convert) ----
    float4 st[8];
    {
        const float4* tb = (const float4*)(train + (size_t)row0 * 500);
#pragma unroll
        for (int i = 0; i < 7; ++i) st[i] = tb[t + i * 512];
        if (t < 416) st[7] = tb[t + 3584];      // 4000 float4 = 32 rows x 125
    }
    uint4 ah4 = ((const uint4*)AGH)[(size_t)row0 * 16 + t];  // 32 rows x 16
    uint4 al4 = ((const uint4*)AGL)[(size_t)row0 * 16 + t];

    // ---- phase 0c: convert staged tile -> TS (row-major [32][520] bf16) ----
    {
        u32* T32 = (u32*)TS;
#pragma unroll
        for (int i = 0; i < 8; ++i) {
            int idx = t + i * 512;
            if (i == 7 && t >= 416) break;
            int r = idx / 125, c4 = idx - r * 125;
            int base = r * 260 + c4 * 2;       // u32 units; row stride 520 u16
            T32[base] = (u32)f2b(st[i].x) | ((u32)f2b(st[i].y) << 16);
            T32[base + 1] = (u32)f2b(st[i].z) | ((u32)f2b(st[i].w) << 16);
        }
        if (t < 192) {                          // zero cols 500..511
            int r = t / 6, c4 = t - r * 6;
            T32[r * 260 + 250 + c4] = 0;
        }
    }
    // ---- phase 0d: SAG fill from global agg (136-stride layout) ----
    {
        int r = t >> 4, c16 = t & 15;
        int base = r * 68 + c16 * 4;            // u32 index (even)
        u32* SH = (u32*)SAGh;
        u32* SL = (u32*)SAGl;
        SH[base] = ah4.x; SH[base + 1] = ah4.y;
        SH[base + 2] = ah4.z; SH[base + 3] = ah4.w;
        SL[base] = al4.x; SL[base + 1] = al4.y;
        SL[base + 2] = al4.z; SL[base + 3] = al4.w;
    }
    __syncthreads();   // TS + SAG ready

    int lane = t & 63, g = t >> 6;  // wave index = col-group 0..7
    int m = lane & 15, q = lane >> 4, n16 = lane & 15;

    int hr0 = m * 136 + q * 8;
    int hr1 = (16 + m) * 136 + q * 8;
    int cr0 = q * 4, cr1 = 16 + q * 4;
    const f32x4 z4 = {0.f, 0.f, 0.f, 0.f};
    f32x4 acc0 = z4, acc1 = z4;
    const u16* tA0 = TS + m * 520 + q * 8;
    const u16* tA1 = TS + (16 + m) * 520 + q * 8;

    // ---- layer1: kk0..15 train (TS), kk16..19 agg (SAG) ----
#pragma unroll
    for (int kk = 0; kk < 16; ++kk) {
        bf16x8 a0 = *(const bf16x8*)(tA0 + kk * 32);
        bf16x8 a1 = *(const bf16x8*)(tA1 + kk * 32);
        size_t bo = ((size_t)(kk * 8 + g) * 64 + lane) * 8;
        bf16x8 bh = *(const bf16x8*)(B1h + bo);
        bf16x8 bl = *(const bf16x8*)(B1l + bo);
        acc0 = __builtin_amdgcn_mfma_f32_16x16x32_bf16(a0, bh, acc0, 0, 0, 0);
        acc0 = __builtin_amdgcn_mfma_f32_16x16x32_bf16(a0, bl, acc0, 0, 0, 0);
        acc1 = __builtin_amdgcn_mfma_f32_16x16x32_bf16(a1, bh, acc1, 0, 0, 0);
        acc1 = __builtin_amdgcn_mfma_f32_16x16x32_bf16(a1, bl, acc1, 0, 0, 0);
    }
#pragma unroll
    for (int kk = 16; kk < 20; ++kk) {
        int o = (kk - 16) * 32;
        bf16x8 ah0 = *(const bf16x8*)(SAGh + hr0 + o);
        bf16x8 al0 = *(const bf16x8*)(SAGl + hr0 + o);
        bf16x8 ah1 = *(const bf16x8*)(SAGh + hr1 + o);
        bf16x8 al1 = *(const bf16x8*)(SAGl + hr1 + o);
        size_t bo = ((size_t)(kk * 8 + g) * 64 + lane) * 8;
        bf16x8 bh = *(const bf16x8*)(B1h + bo);
        bf16x8 bl = *(const bf16x8*)(B1l + bo);
        acc0 = __builtin_amdgcn_mfma_f32_16x16x32_bf16(ah0, bh, acc0, 0, 0, 0);
        acc0 = __builtin_amdgcn_mfma_f32_16x16x32_bf16(ah0, bl, acc0, 0, 0, 0);
        acc0 = __builtin_amdgcn_mfma_f32_16x16x32_bf16(al0, bh, acc0, 0, 0, 0);
        acc1 = __builtin_amdgcn_mfma_f32_16x16x32_bf16(ah1, bh, acc1, 0, 0, 0);
        acc1 = __builtin_amdgcn_mfma_f32_16x16x32_bf16(ah1, bl, acc1, 0, 0, 0);
        acc1 = __builtin_amdgcn_mfma_f32_16x16x32_bf16(al1, bh, acc1, 0, 0, 0);
    }
    __syncthreads();   // all TS reads done -> S1 overlay safe
    {
        int n = g * 16 + n16;
        float bias = b1[n];
#pragma unroll
        for (int rg = 0; rg < 4; ++rg) {
            float v0 = acc0[rg] + bias; v0 = v0 > 0.f ? v0 : 0.f;
            float v1 = acc1[rg] + bias; v1 = v1 > 0.f ? v1 : 0.f;
            u16 h0 = f2b(v0), h1v = f2b(v1);
            S1h[(cr0 + rg) * 136 + n] = h0; S1l[(cr0 + rg) * 136 + n] = f2b(v0 - b2f(h0));
            S1h[(cr1 + rg) * 136 + n] = h1v; S1l[(cr1 + rg) * 136 + n] = f2b(v1 - b2f(h1v));
        }
    }
    __syncthreads();

    // ---- layer2: K=256 (h1 kk0..3 S1; agg kk4..7 SAG) ----
    acc0 = z4; acc1 = z4;
#pragma unroll
    for (int kk = 0; kk < 8; ++kk) {
        const u16* Ph = (kk < 4) ? S1h : SAGh;
        const u16* Pl = (kk < 4) ? S1l : SAGl;
        int o = (kk & 3) * 32;
        bf16x8 ah0 = *(const bf16x8*)(Ph + hr0 + o);
        bf16x8 al0 = *(const bf16x8*)(Pl + hr0 + o);
        bf16x8 ah1 = *(const bf16x8*)(Ph + hr1 + o);
        bf16x8 al1 = *(const bf16x8*)(Pl + hr1 + o);
        size_t bo = ((size_t)(kk * 8 + g) * 64 + lane) * 8;
        bf16x8 bh = *(const bf16x8*)(B2h + bo);
        bf16x8 bl = *(const bf16x8*)(B2l + bo);
        acc0 = __builtin_amdgcn_mfma_f32_16x16x32_bf16(ah0, bh, acc0, 0, 0, 0);
        acc0 = __builtin_amdgcn_mfma_f32_16x16x32_bf16(ah0, bl, acc0, 0, 0, 0);
        acc0 = __builtin_amdgcn_mfma_f32_16x16x32_bf16(al0, bh, acc0, 0, 0, 0);
        acc1 = __builtin_amdgcn_mfma_f32_16x16x32_bf16(ah1, bh, acc1, 0, 0, 0);
        acc1 = __builtin_amdgcn_mfma_f32_16x16x32_bf16(ah1, bl, acc1, 0, 0, 0);
        acc1 = __builtin_amdgcn_mfma_f32_16x16x32_bf16(al1, bh, acc1, 0, 0, 0);
    }
    {
        int n = g * 16 + n16;
        float bias = b2[n];
#pragma unroll
        for (int rg = 0; rg < 4; ++rg) {
            float v0 = acc0[rg] + bias; v0 = v0 > 0.f ? v0 : 0.f;
            float v1 = acc1[rg] + bias; v1 = v1 > 0.f ? v1 : 0.f;
            u16 h0 = f2b(v0), h1v = f2b(v1);
            S2h[(cr0 + rg) * 136 + n] = h0; S2l[(cr0 + rg) * 136 + n] = f2b(v0 - b2f(h0));
            S2h[(cr1 + rg) * 136 + n] = h1v; S2l[(cr1 + rg) * 136 + n] = f2b(v1 - b2f(h1v));
        }
    }
    __syncthreads();

    // ---- layer3: K=128 (h2 S2) -> S1 ----
    acc0 = z4; acc1 = z4;
#pragma unroll
    for (int kk = 0; kk < 4; ++kk) {
        int o = kk * 32;
        bf16x8 ah0 = *(const bf16x8*)(S2h + hr0 + o);
        bf16x8 al0 = *(const bf16x8*)(S2l + hr0 + o);
        bf16x8 ah1 = *(const bf16x8*)(S2h + hr1 + o);
        bf16x8 al1 = *(const bf16x8*)(S2l + hr1 + o);
        size_t bo = ((size_t)(kk * 8 + g) * 64 + lane) * 8;
        bf16x8 bh = *(const bf16x8*)(B3h + bo);
        bf16x8 bl = *(const bf16x8*)(B3l + bo);
        acc0 = __builtin_amdgcn_mfma_f32_16x16x32_bf16(ah0, bh, acc0, 0, 0, 0);
        acc0 = __builtin_amdgcn_mfma_f32_16x16x32_bf16(ah0, bl, acc0, 0, 0, 0);
        acc0 = __builtin_amdgcn_mfma_f32_16x16x32_bf16(al0, bh, acc0, 0, 0, 0);
        acc1 = __builtin_amdgcn_mfma_f32_16x16x32_bf16(ah1, bh, acc1, 0, 0, 0);
        acc1 = __builtin_amdgcn_mfma_f32_16x16x32_bf16(ah1, bl, acc1, 0, 0, 0);
        acc1 = __builtin_amdgcn_mfma_f32_16x16x32_bf16(al1, bh, acc1, 0, 0, 0);
    }
    {
        int n = g * 16 + n16;
        float bias = bc1[n];
#pragma unroll
        for (int rg = 0; rg < 4; ++rg) {
            float v0 = acc0[rg] + bias; v0 = v0 > 0.f ? v0 : 0.f;
            float v1 = acc1[rg] + bias; v1 = v1 > 0.f ? v1 : 0.f;
            u16 h0 = f2b(v0), h1v = f2b(v1);
            S1h[(cr0 + rg) * 136 + n] = h0; S1l[(cr0 + rg) * 136 + n] = f2b(v0 - b2f(h0));
            S1h[(cr1 + rg) * 136 + n] = h1v; S1l[(cr1 + rg) * 136 + n] = f2b(v1 - b2f(h1v));
        }
    }
    __syncthreads();

    // ---- layer4: K=128, N=16 (waves 0,1 = tiles 0,1) ----
    if (g < 2) {
        int hr = (g == 0) ? hr0 : hr1;
        int cr = (g == 0) ? cr0 : cr1;
        f32x4 a4 = z4;
#pragma unroll
        for (int kk = 0; kk < 4; ++kk) {
            bf16x8 ah = *(const bf16x8*)(S1h + hr + kk * 32);
            bf16x8 al = *(const bf16x8*)(S1l + hr + kk * 32);
            size_t bo = ((size_t)kk * 64 + lane) * 8;
            bf16x8 bh = *(const bf16x8*)(B4h + bo);
            bf16x8 bl = *(const bf16x8*)(B4l + bo);
            a4 = __builtin_amdgcn_mfma_f32_16x16x32_bf16(ah, bh, a4, 0, 0, 0);
            a4 = __builtin_amdgcn_mfma_f32_16x16x32_bf16(ah, bl, a4, 0, 0, 0);
            a4 = __builtin_amdgcn_mfma_f32_16x16x32_bf16(al, bh, a4, 0, 0, 0);
        }
        float bias = bc2[n16];
#pragma unroll
        for (int rg = 0; rg < 4; ++rg)
            out[(size_t)(row0 + cr + rg) * NCLS + n16] = a4[rg] + bias;
    }
}

extern "C" void kernel_launch(void* const* d_in, const int* in_sizes, int n_in,
                              void* d_out, int out_size, void* d_ws, size_t ws_size,
                              hipStream_t stream) {
    const float* gene = (const float*)d_in[0];
    const float* train = (const float*)d_in[1];
    const int* esrc = (const int*)d_in[2];
    const int* edst = (const int*)d_in[3];

    char* ws = (char*)d_ws;
    int* bcnt = (int*)(ws + 0);             //     2500 (pad 4096)
    u32* hist = (u32*)(ws + 4096);          //  1562500 (625*625*4)
    u32* boff = (u32*)(ws + 1566720);       //  1562500
    u32* bkt = (u32*)(ws + 3129344);        //  3840000 (625*1536*4)
    u16* GH = (u16*)(ws + 6969344);         //   640000 (2500*128 u16)
    u32* AGH = (u32*)(ws + 7609344);        //  5120000 (20000*64 u32)
    u32* AGL = (u32*)(ws + 12729344);       //  5120000
    u16* B1h = (u16*)(ws + 17849344);       //   163840
    u16* B1l = (u16*)(ws + 18013184);       //   163840
    u16* B2h = (u16*)(ws + 18177024);       //    65536
    u16* B2l = (u16*)(ws + 18242560);       //    65536
    u16* B3h = (u16*)(ws + 18308096);       //    32768
    u16* B3l = (u16*)(ws + 18340864);       //    32768
    u16* B4h = (u16*)(ws + 18373632);       //     4096
    u16* B4l = (u16*)(ws + 18377728);       //     4096
    // total 18,381,824 B; no memset needed (all buffers fully rewritten)

    k_prep<<<NEB + GNB + PKB, 256, 0, stream>>>(
        edst, hist, gene, (u32*)GH,
        (const float*)d_in[4], (const float*)d_in[5], (const float*)d_in[7],
        (const float*)d_in[8], (const float*)d_in[10], (const float*)d_in[12],
        B1h, B1l, B2h, B2l, B3h, B3l, B4h, B4l);
    k_scan<<<NBIN, 256, 0, stream>>>(hist, boff, bcnt);
    k_scat<<<NEB, 256, 0, stream>>>(esrc, edst, boff, bkt);
    k_agg<<<NT / 16, 256, 0, stream>>>(bcnt, bkt, GH, AGH, AGL);
    k_mlp<<<NT / 32, 512, 0, stream>>>(
        AGH, AGL, train, B1h, B1l, B2h, B2l, B3h, B3l, B4h, B4l,
        (const float*)d_in[6], (const float*)d_in[9], (const float*)d_in[11],
        (const float*)d_in[13], (float*)d_out);
}